// Round 3
// baseline (381.797 us; speedup 1.0000x reference)
//
#include <hip/hip_runtime.h>

// Fused 7-layer 1x1-conv chain, round 6: persistent blocks + distance-3 chunk ring.
//  - Grid = 512 blocks (exactly 2/CU, no relaunch); block owns one 128-px column,
//    loops over 8 batches (TPB=8 tiles). Weights loaded+converted ONCE per block.
//  - Per wave: ring-3 of 4 KiB x-chunk buffers. Chunk g lives in buf g%3, and
//    (g+3)%3 == g%3, so the schedule is: wait(g) -> compute(g) from buf bi ->
//    STAGE(g+3) into the SAME buf bi -> rotate bi. Issue-to-wait distance = 3
//    chunk computes (~900-1000 cyc) >= HBM latency, vs ring-2's ~300 cyc. This
//    removes the ~500 cyc/chunk vmcnt stall that dominated round 5.
//  - vmcnt gates (audited, in-order retirement; younger ops = stage quads + 1
//    out-store/tile): steady state kc<3 -> vmcnt(9), kc==3 -> vmcnt(8); tile 0
//    all vmcnt(8) (no store in flight yet); last tile kc==2 -> vmcnt(5),
//    kc==3 -> vmcnt(0). Never drained mid-loop. No __syncthreads after the
//    one-time tw barrier; all LDS wave-private.
//  - px XOR-swizzle (LDS[ch][u] = x[ch][u ^ 8*(chgrp&3)]) via pre-swizzled GLOBAL
//    source (global_load_lds dest must stay lane-linear): L1 B-frag ds_read
//    4-way -> 2-way (free per m136).
//  - Epilogue scratch separate (all 3 ring bufs hold in-flight next-tile data
//    during the epilogue). LDS 65.7 KiB -> 2 blocks/CU.
//
// MFMA 16x16x32 layouts: A[m][k]: m=lane&15, k=(lane>>4)*8+j
//                        B[k][n]: n=lane&15, k=(lane>>4)*8+j
//                        C/D: col=lane&15, row=(lane>>4)*4+reg

#define NEG_SLOPE 0.01f
constexpr int HW = 65536;                     // 256*256
constexpr int GRID = 512;                     // 2 blocks/CU exactly
constexpr int TPB  = 8;                       // tiles per block (= batch count)
constexpr size_t TSTRIDE = (size_t)128 * HW;  // floats between a block's tiles

typedef __attribute__((ext_vector_type(8))) short bf16x8;
typedef __attribute__((ext_vector_type(4))) float f32x4;
typedef __attribute__((ext_vector_type(2))) float f32x2;

__device__ __forceinline__ float leaky(float v) { return fmaxf(v, v * NEG_SLOPE); }

// fp32 pair -> packed bf16x2 (compiler emits v_cvt_pk_bf16_f32; m240: no hand asm)
__device__ __forceinline__ unsigned pk2(float a, float b) {
    __bf16 ba = (__bf16)a, bb = (__bf16)b;
    unsigned short ua = __builtin_bit_cast(unsigned short, ba);
    unsigned short ub = __builtin_bit_cast(unsigned short, bb);
    return (unsigned)ua | ((unsigned)ub << 16);
}

// A-frag from o-major fp32 weight matrix W[m][k] (row length C); k 8-aligned
__device__ __forceinline__ bf16x8 loadA(const float* __restrict__ wsrc, int C, int m, int k) {
    f32x4 lo = *(const f32x4*)(wsrc + m * C + k);
    f32x4 hi = *(const f32x4*)(wsrc + m * C + k + 4);
    union { bf16x8 v; unsigned u[4]; } r;
    r.u[0] = pk2(lo[0], lo[1]); r.u[1] = pk2(lo[2], lo[3]);
    r.u[2] = pk2(hi[0], hi[1]); r.u[3] = pk2(hi[2], hi[3]);
    return r.v;
}

__device__ __forceinline__ void async_cp16(const float* g, float* l) {
    __builtin_amdgcn_global_load_lds((const __attribute__((address_space(1))) unsigned*)g,
                                     (__attribute__((address_space(3))) unsigned*)l,
                                     16, 0, 0);
}

// 0-instruction compiler memory fence (stops TBAA cross-type reordering)
__device__ __forceinline__ void cfence() { asm volatile("" ::: "memory"); }

__global__ __launch_bounds__(256, 2) void fused_ring3_kernel(
    const float* __restrict__ x,
    const float* __restrict__ w1, const float* __restrict__ w2,
    const float* __restrict__ w3, const float* __restrict__ w4,
    const float* __restrict__ w5, const float* __restrict__ w6,
    const float* __restrict__ w7, float* __restrict__ out) {
    __shared__ float lds_x[4][3][1024];  // per-wave ring-3: [32 ch][32 px] fp32 (px swizzled)
    __shared__ float lds_s[4][1088];     // per-wave epilogue scratch h1/h2/h3 (4352 B)
    __shared__ float lds_tw[176];        // tail weights w4|w5|w6|w7

    const int tid = threadIdx.x;
    if (tid < 128)      lds_tw[tid] = w4[tid];
    else if (tid < 160) lds_tw[tid] = w5[tid - 128];
    else if (tid < 168) lds_tw[tid] = w6[tid - 160];
    else if (tid < 170) lds_tw[tid] = w7[tid - 168];

    const int w    = tid >> 6;
    const int lane = tid & 63;
    const int n    = lane & 15;       // frag minor index
    const int q    = lane >> 4;       // quad
    const int pl   = lane & 31;
    const int r    = lane >> 3;       // stage: channel row within instr
    const int s4   = (lane & 7) * 4;  // stage: 4-px slot

    const int b = blockIdx.x;
    // tile it: px0 = b*128 + it*65536 -> batch=it, pin=b*128
    const float* xg = x + b * 128 + w * 32;  // + it*TSTRIDE + ch*HW

    __syncthreads();  // lds_tw visible (before any counted VMEM issue)

    // ---- weights once per block: 42 dwordx4 loads + cvt (amortized over 8 tiles) ----
    bf16x8 a1[4][4];  // L1: M=64 (4 Mt) x K=128 (4 kc)
#pragma unroll
    for (int Mt = 0; Mt < 4; ++Mt)
#pragma unroll
        for (int kc = 0; kc < 4; ++kc)
            a1[Mt][kc] = loadA(w1, 128, Mt * 16 + n, kc * 32 + q * 8);
    bf16x8 a2[2][2];  // L2: M=32 x K=64
#pragma unroll
    for (int Mt = 0; Mt < 2; ++Mt)
#pragma unroll
        for (int kc = 0; kc < 2; ++kc)
            a2[Mt][kc] = loadA(w2, 64, Mt * 16 + n, kc * 32 + q * 8);
    bf16x8 a3 = loadA(w3, 32, n, q * 8);  // L3: M=16 x K=32
    cfence();
    __builtin_amdgcn_sched_barrier(0);

    // stage chunk (channels KCX*32..+31, 32 px) of tile at BASE into ring buf BUF.
    // instr i_: channels KCX*32 + i_*8 + r; LDS dest lane-linear (base + lane*16B);
    // global px slot pre-swizzled s4 ^ (i_*8) so LDS[ch][u] = x[ch][u ^ 8*chgrp].
    float* ldsw = &lds_x[w][0][0];
#define STAGE(BASE, KCX, BUF) do {                                                   \
        const float* gb_ = (BASE) + (size_t)((KCX) * 32 + r) * HW;                   \
        float* lb_ = ldsw + (BUF) * 1024;                                            \
        _Pragma("unroll")                                                            \
        for (int i_ = 0; i_ < 4; ++i_)                                               \
            async_cp16(gb_ + (size_t)(i_ * 8) * HW + (s4 ^ (i_ * 8)), lb_ + i_ * 256); \
    } while (0)

    // prologue: chunks 0,1,2 of tile 0 -> bufs 0,1,2
    STAGE(xg, 0, 0);
    STAGE(xg, 1, 1);
    STAGE(xg, 2, 2);
    cfence();

    const int pq = q * 8;
    int bi = 0;  // buffer of the chunk about to be computed (= g % 3)

    for (int it = 0; it < TPB; ++it) {
        const float* xg_it = xg + (size_t)it * TSTRIDE;
        const float* xg_nt = xg_it + TSTRIDE;

        f32x4 acc1[4][2];
#pragma unroll
        for (int Mt = 0; Mt < 4; ++Mt)
#pragma unroll
            for (int Nt = 0; Nt < 2; ++Nt) acc1[Mt][Nt] = (f32x4){0.f, 0.f, 0.f, 0.f};

#pragma unroll
        for (int kc = 0; kc < 4; ++kc) {
            // gate chunk g=4it+kc (audited younger-op counts; see header)
            if (kc < 2) {
                if (it == 0) asm volatile("s_waitcnt vmcnt(8)" ::: "memory");
                else         asm volatile("s_waitcnt vmcnt(9)" ::: "memory");
            } else if (kc == 2) {
                if (it == 0)            asm volatile("s_waitcnt vmcnt(8)" ::: "memory");
                else if (it == TPB - 1) asm volatile("s_waitcnt vmcnt(5)" ::: "memory");
                else                    asm volatile("s_waitcnt vmcnt(9)" ::: "memory");
            } else {
                if (it == TPB - 1) asm volatile("s_waitcnt vmcnt(0)" ::: "memory");
                else               asm volatile("s_waitcnt vmcnt(8)" ::: "memory");
            }
            __builtin_amdgcn_sched_barrier(0);

            const float* xb = ldsw + bi * 1024;
#pragma unroll
            for (int Nt = 0; Nt < 2; ++Nt) {
                const int pxsw = (Nt * 16 + n) ^ pq;  // swizzled px slot (2-way banks = free)
                float t[8];
#pragma unroll
                for (int j = 0; j < 8; ++j)
                    t[j] = xb[(pq + j) * 32 + pxsw];
                union { bf16x8 v; unsigned u[4]; } bb;
                bb.u[0] = pk2(t[0], t[1]); bb.u[1] = pk2(t[2], t[3]);
                bb.u[2] = pk2(t[4], t[5]); bb.u[3] = pk2(t[6], t[7]);
#pragma unroll
                for (int Mt = 0; Mt < 4; ++Mt)
                    acc1[Mt][Nt] = __builtin_amdgcn_mfma_f32_16x16x32_bf16(a1[Mt][kc], bb.v, acc1[Mt][Nt], 0, 0, 0);
            }
            __builtin_amdgcn_sched_barrier(0);

            // issue chunk g+3 into the buffer just consumed ((g+3)%3 == g%3):
            // kc==0 -> this tile chunk 3; kc>=1 -> next tile chunk kc-1.
            if (kc == 0)           STAGE(xg_it, 3, bi);
            else if (it < TPB - 1) STAGE(xg_nt, kc - 1, bi);
            cfence();
            bi = (bi == 2) ? 0 : bi + 1;
        }

        // ---- epilogue (wave-private scratch; per-wave DS in-order => no barriers) ----
        float* Sw = &lds_s[w][0];
        short* h1 = (short*)Sw;  // [32 px][64 ch] stride 68 shorts
#pragma unroll
        for (int Mt = 0; Mt < 4; ++Mt)
#pragma unroll
            for (int Nt = 0; Nt < 2; ++Nt) {
                int px = Nt * 16 + n;
                uint2 v;
                v.x = pk2(leaky(acc1[Mt][Nt][0]), leaky(acc1[Mt][Nt][1]));
                v.y = pk2(leaky(acc1[Mt][Nt][2]), leaky(acc1[Mt][Nt][3]));
                *(uint2*)(h1 + px * 68 + Mt * 16 + q * 4) = v;  // 8B-aligned
            }
        cfence();

        f32x4 acc2[2][2];
#pragma unroll
        for (int Mt = 0; Mt < 2; ++Mt)
#pragma unroll
            for (int Nt = 0; Nt < 2; ++Nt) acc2[Mt][Nt] = (f32x4){0.f, 0.f, 0.f, 0.f};
#pragma unroll
        for (int Nt = 0; Nt < 2; ++Nt)
#pragma unroll
            for (int kc = 0; kc < 2; ++kc) {
                int off = (Nt * 16 + n) * 68 + kc * 32 + q * 8;
                uint2 lo = *(const uint2*)(h1 + off);
                uint2 hi = *(const uint2*)(h1 + off + 4);
                union { bf16x8 v; unsigned u[4]; } bb;
                bb.u[0] = lo.x; bb.u[1] = lo.y; bb.u[2] = hi.x; bb.u[3] = hi.y;
#pragma unroll
                for (int Mt = 0; Mt < 2; ++Mt)
                    acc2[Mt][Nt] = __builtin_amdgcn_mfma_f32_16x16x32_bf16(a2[Mt][kc], bb.v, acc2[Mt][Nt], 0, 0, 0);
            }
        cfence();

        short* h2 = (short*)Sw;  // [32 px][32 ch] stride 36 shorts
#pragma unroll
        for (int Mt = 0; Mt < 2; ++Mt)
#pragma unroll
            for (int Nt = 0; Nt < 2; ++Nt) {
                int px = Nt * 16 + n;
                uint2 v;
                v.x = pk2(leaky(acc2[Mt][Nt][0]), leaky(acc2[Mt][Nt][1]));
                v.y = pk2(leaky(acc2[Mt][Nt][2]), leaky(acc2[Mt][Nt][3]));
                *(uint2*)(h2 + px * 36 + Mt * 16 + q * 4) = v;
            }
        cfence();

        f32x4 acc3[2];
#pragma unroll
        for (int Nt = 0; Nt < 2; ++Nt) {
            int off = (Nt * 16 + n) * 36 + q * 8;
            uint2 lo = *(const uint2*)(h2 + off);
            uint2 hi = *(const uint2*)(h2 + off + 4);
            union { bf16x8 v; unsigned u[4]; } bb;
            bb.u[0] = lo.x; bb.u[1] = lo.y; bb.u[2] = hi.x; bb.u[3] = hi.y;
            f32x4 zero = {0.f, 0.f, 0.f, 0.f};
            acc3[Nt] = __builtin_amdgcn_mfma_f32_16x16x32_bf16(a3, bb.v, zero, 0, 0, 0);
        }
        cfence();

        float* h3 = Sw;  // [32 px][16 ch] stride 18 floats
#pragma unroll
        for (int Nt = 0; Nt < 2; ++Nt) {
            int px = Nt * 16 + n;
            f32x2 va = {leaky(acc3[Nt][0]), leaky(acc3[Nt][1])};
            f32x2 vb = {leaky(acc3[Nt][2]), leaky(acc3[Nt][3])};
            *(f32x2*)(h3 + px * 18 + q * 4)     = va;
            *(f32x2*)(h3 + px * 18 + q * 4 + 2) = vb;
        }
        cfence();

        // ---- tail L4-L7, one px per lane (halves duplicate; lower half stores) ----
        float hh[16];
#pragma unroll
        for (int c = 0; c < 16; ++c) hh[c] = h3[pl * 18 + c];

        float g4[8];
#pragma unroll
        for (int o = 0; o < 8; ++o) {
            float a = 0.f;
#pragma unroll
            for (int c = 0; c < 16; ++c) a = fmaf(lds_tw[o * 16 + c], hh[c], a);
            g4[o] = leaky(a);
        }
        float g5[4];
#pragma unroll
        for (int o = 0; o < 4; ++o) {
            float a = 0.f;
#pragma unroll
            for (int c = 0; c < 8; ++c) a = fmaf(lds_tw[128 + o * 8 + c], g4[c], a);
            g5[o] = leaky(a);
        }
        float g6[2];
#pragma unroll
        for (int o = 0; o < 2; ++o) {
            float a = 0.f;
#pragma unroll
            for (int c = 0; c < 4; ++c) a = fmaf(lds_tw[160 + o * 4 + c], g5[c], a);
            g6[o] = leaky(a);
        }
        float res = fmaf(lds_tw[168], g6[0], lds_tw[169] * g6[1]);
        if (lane < 32) out[b * 128 + it * 65536 + w * 32 + pl] = res;  // 1 VMEM op (counted)
        cfence();
    }
#undef STAGE
}

extern "C" void kernel_launch(void* const* d_in, const int* in_sizes, int n_in,
                              void* d_out, int out_size, void* d_ws, size_t ws_size,
                              hipStream_t stream) {
    const float* x  = (const float*)d_in[0];
    const float* w1 = (const float*)d_in[1];
    const float* w2 = (const float*)d_in[2];
    const float* w3 = (const float*)d_in[3];
    const float* w4 = (const float*)d_in[4];
    const float* w5 = (const float*)d_in[5];
    const float* w6 = (const float*)d_in[6];
    const float* w7 = (const float*)d_in[7];
    float* out = (float*)d_out;

    fused_ring3_kernel<<<GRID, 256, 0, stream>>>(x, w1, w2, w3, w4, w5, w6, w7, out);
}

// Round 5
// 377.951 us; speedup vs baseline: 1.0102x; 1.0102x over previous
//
#include <hip/hip_runtime.h>

// Fused 7-layer 1x1-conv chain, round 8 (= round 7 resubmitted; round-7 bench was
// an infra failure "container failed twice" — kernel audited: no hang paths, no
// OOB, vmcnt gates re-verified op-by-op).
//  - Persistent: grid=512 (2 blocks/CU), block owns a 128-px column, loops 8
//    batches. Weights converted once per block. Per-wave ring-3 of 4 KiB chunks.
//  - KEY CHANGE vs round 6: stage issue points are SPREAD across the whole tile
//    instead of bunched in the L1 phase. Round-6 issued all 16 stages during the
//    ~600-cyc chunk loop, then went VMEM-silent for the ~1800-cyc epilogue+tail;
//    with 8 phase-correlated waves/CU that idles HBM ~40-60% (measured ~4.2 TB/s
//    effective vs 6.3 achievable). New schedule per tile t:
//      kc0: compute(t,0) -> STAGE(t,3)        [WAR: earliest legal]
//      h1 done          -> STAGE(t+1,0)       [buf of (t,1), free since kc1]
//      L2 done          -> STAGE(t+1,1)       [buf of (t,2)]
//      h3 done          -> STAGE(t+1,2)       [buf of (t,3)]
//    Every delayed stage still has >=1000 cyc issue->wait distance.
//  - vmcnt gates (audited, in-order retirement; buf(g)=(t+kc)%3):
//      steady state (t>=1): kc0,kc1 -> vmcnt(9); kc2 -> vmcnt(5); kc3 -> vmcnt(0)
//      tile 0:              kc0,kc1 -> vmcnt(8); kc2 -> vmcnt(4); kc3 -> vmcnt(0)
//    kc3's vmcnt(0) == "wait chunk (t,3)" exactly: nothing younger is in flight.
//  - Tail L4-L7 split across half-waves (was duplicated): each half sums half of
//    K, combined with __shfl_xor(...,32). 85 tw ds_reads + 85 fma vs 170+170.
//  - px XOR-swizzle via pre-swizzled GLOBAL source (dest lane-linear), L1 B-frag
//    ds_read 4-way -> 2-way. Epilogue scratch separate from ring (in-flight data).
//    LDS 65.7 KiB -> 2 blocks/CU.
//
// MFMA 16x16x32 layouts: A[m][k]: m=lane&15, k=(lane>>4)*8+j
//                        B[k][n]: n=lane&15, k=(lane>>4)*8+j
//                        C/D: col=lane&15, row=(lane>>4)*4+reg

#define NEG_SLOPE 0.01f
constexpr int HW = 65536;                     // 256*256
constexpr int GRID = 512;                     // 2 blocks/CU exactly
constexpr int TPB  = 8;                       // tiles per block (= batch count)
constexpr size_t TSTRIDE = (size_t)128 * HW;  // floats between a block's tiles

typedef __attribute__((ext_vector_type(8))) short bf16x8;
typedef __attribute__((ext_vector_type(4))) float f32x4;
typedef __attribute__((ext_vector_type(2))) float f32x2;

__device__ __forceinline__ float leaky(float v) { return fmaxf(v, v * NEG_SLOPE); }

// fp32 pair -> packed bf16x2 (compiler emits v_cvt_pk_bf16_f32; m240: no hand asm)
__device__ __forceinline__ unsigned pk2(float a, float b) {
    __bf16 ba = (__bf16)a, bb = (__bf16)b;
    unsigned short ua = __builtin_bit_cast(unsigned short, ba);
    unsigned short ub = __builtin_bit_cast(unsigned short, bb);
    return (unsigned)ua | ((unsigned)ub << 16);
}

// A-frag from o-major fp32 weight matrix W[m][k] (row length C); k 8-aligned
__device__ __forceinline__ bf16x8 loadA(const float* __restrict__ wsrc, int C, int m, int k) {
    f32x4 lo = *(const f32x4*)(wsrc + m * C + k);
    f32x4 hi = *(const f32x4*)(wsrc + m * C + k + 4);
    union { bf16x8 v; unsigned u[4]; } r;
    r.u[0] = pk2(lo[0], lo[1]); r.u[1] = pk2(lo[2], lo[3]);
    r.u[2] = pk2(hi[0], hi[1]); r.u[3] = pk2(hi[2], hi[3]);
    return r.v;
}

__device__ __forceinline__ void async_cp16(const float* g, float* l) {
    __builtin_amdgcn_global_load_lds((const __attribute__((address_space(1))) unsigned*)g,
                                     (__attribute__((address_space(3))) unsigned*)l,
                                     16, 0, 0);
}

// 0-instruction compiler memory fence (stops TBAA cross-type reordering)
__device__ __forceinline__ void cfence() { asm volatile("" ::: "memory"); }

__global__ __launch_bounds__(256, 2) void fused_spread_kernel(
    const float* __restrict__ x,
    const float* __restrict__ w1, const float* __restrict__ w2,
    const float* __restrict__ w3, const float* __restrict__ w4,
    const float* __restrict__ w5, const float* __restrict__ w6,
    const float* __restrict__ w7, float* __restrict__ out) {
    __shared__ float lds_x[4][3][1024];  // per-wave ring-3: [32 ch][32 px] fp32 (px swizzled)
    __shared__ float lds_s[4][1088];     // per-wave epilogue scratch h1/h2/h3 (4352 B)
    __shared__ float lds_tw[176];        // tail weights w4|w5|w6|w7

    const int tid = threadIdx.x;
    if (tid < 128)      lds_tw[tid] = w4[tid];
    else if (tid < 160) lds_tw[tid] = w5[tid - 128];
    else if (tid < 168) lds_tw[tid] = w6[tid - 160];
    else if (tid < 170) lds_tw[tid] = w7[tid - 168];

    const int w    = tid >> 6;
    const int lane = tid & 63;
    const int n    = lane & 15;       // frag minor index
    const int q    = lane >> 4;       // quad
    const int pl   = lane & 31;
    const int half = lane >> 5;
    const int r    = lane >> 3;       // stage: channel row within instr
    const int s4   = (lane & 7) * 4;  // stage: 4-px slot

    const int b = blockIdx.x;
    // tile it: px0 = b*128 + it*65536 -> batch=it, pin=b*128
    const float* xg = x + b * 128 + w * 32;  // + it*TSTRIDE + ch*HW

    __syncthreads();  // lds_tw visible (before any counted VMEM issue)

    // ---- weights once per block (amortized over 8 tiles; L2-hot) ----
    bf16x8 a1[4][4];  // L1: M=64 (4 Mt) x K=128 (4 kc)
#pragma unroll
    for (int Mt = 0; Mt < 4; ++Mt)
#pragma unroll
        for (int kc = 0; kc < 4; ++kc)
            a1[Mt][kc] = loadA(w1, 128, Mt * 16 + n, kc * 32 + q * 8);
    bf16x8 a2[2][2];  // L2: M=32 x K=64
#pragma unroll
    for (int Mt = 0; Mt < 2; ++Mt)
#pragma unroll
        for (int kc = 0; kc < 2; ++kc)
            a2[Mt][kc] = loadA(w2, 64, Mt * 16 + n, kc * 32 + q * 8);
    bf16x8 a3 = loadA(w3, 32, n, q * 8);  // L3: M=16 x K=32
    cfence();
    __builtin_amdgcn_sched_barrier(0);

    // stage chunk (channels KCX*32..+31, 32 px) of tile at BASE into ring buf BUF.
    // instr i_: channels KCX*32 + i_*8 + r; LDS dest lane-linear (base + lane*16B);
    // global px slot pre-swizzled s4 ^ (i_*8) so LDS[ch][u] = x[ch][u ^ 8*chgrp].
    float* ldsw = &lds_x[w][0][0];
#define STAGE(BASE, KCX, BUF) do {                                                   \
        const float* gb_ = (BASE) + (size_t)((KCX) * 32 + r) * HW;                   \
        float* lb_ = ldsw + (BUF) * 1024;                                            \
        _Pragma("unroll")                                                            \
        for (int i_ = 0; i_ < 4; ++i_)                                               \
            async_cp16(gb_ + (size_t)(i_ * 8) * HW + (s4 ^ (i_ * 8)), lb_ + i_ * 256); \
    } while (0)

    // prologue: chunks 0,1,2 of tile 0 -> bufs 0,1,2  (buf(g) = (t+kc)%3, t=0)
    STAGE(xg, 0, 0);
    STAGE(xg, 1, 1);
    STAGE(xg, 2, 2);
    cfence();

    const int pq = q * 8;
    int bt = 0;  // buf of chunk (t,0) = t%3

    for (int it = 0; it < TPB; ++it) {
        const float* xg_it = xg + (size_t)it * TSTRIDE;
        const float* xg_nt = xg_it + TSTRIDE;
        const bool   more  = (it < TPB - 1);

        int b1 = bt + 1; if (b1 >= 3) b1 -= 3;
        int b2 = bt + 2; if (b2 >= 3) b2 -= 3;
        const int bufk[4] = {bt, b1, b2, bt};  // compute buffers for kc=0..3

        f32x4 acc1[4][2];
#pragma unroll
        for (int Mt = 0; Mt < 4; ++Mt)
#pragma unroll
            for (int Nt = 0; Nt < 2; ++Nt) acc1[Mt][Nt] = (f32x4){0.f, 0.f, 0.f, 0.f};

#pragma unroll
        for (int kc = 0; kc < 4; ++kc) {
            // gate chunk (it,kc); audited younger-op counts (see header)
            if (kc <= 1) {
                if (it == 0) asm volatile("s_waitcnt vmcnt(8)" ::: "memory");
                else         asm volatile("s_waitcnt vmcnt(9)" ::: "memory");
            } else if (kc == 2) {
                if (it == 0) asm volatile("s_waitcnt vmcnt(4)" ::: "memory");
                else         asm volatile("s_waitcnt vmcnt(5)" ::: "memory");
            } else {
                asm volatile("s_waitcnt vmcnt(0)" ::: "memory");  // == wait chunk (t,3)
            }
            __builtin_amdgcn_sched_barrier(0);

            const float* xb = ldsw + bufk[kc] * 1024;
#pragma unroll
            for (int Nt = 0; Nt < 2; ++Nt) {
                const int pxsw = (Nt * 16 + n) ^ pq;  // swizzled px slot (2-way banks = free)
                float t[8];
#pragma unroll
                for (int j = 0; j < 8; ++j)
                    t[j] = xb[(pq + j) * 32 + pxsw];
                union { bf16x8 v; unsigned u[4]; } bb;
                bb.u[0] = pk2(t[0], t[1]); bb.u[1] = pk2(t[2], t[3]);
                bb.u[2] = pk2(t[4], t[5]); bb.u[3] = pk2(t[6], t[7]);
#pragma unroll
                for (int Mt = 0; Mt < 4; ++Mt)
                    acc1[Mt][Nt] = __builtin_amdgcn_mfma_f32_16x16x32_bf16(a1[Mt][kc], bb.v, acc1[Mt][Nt], 0, 0, 0);
            }
            __builtin_amdgcn_sched_barrier(0);

            // only chunk (t,3) is staged inside the L1 phase (WAR on buf bt).
            if (kc == 0) { STAGE(xg_it, 3, bt); cfence(); }
        }

        // ---- epilogue (wave-private scratch; per-wave DS in-order => no barriers) ----
        float* Sw = &lds_s[w][0];
        short* h1 = (short*)Sw;  // [32 px][64 ch] stride 68 shorts
#pragma unroll
        for (int Mt = 0; Mt < 4; ++Mt)
#pragma unroll
            for (int Nt = 0; Nt < 2; ++Nt) {
                int px = Nt * 16 + n;
                uint2 v;
                v.x = pk2(leaky(acc1[Mt][Nt][0]), leaky(acc1[Mt][Nt][1]));
                v.y = pk2(leaky(acc1[Mt][Nt][2]), leaky(acc1[Mt][Nt][3]));
                *(uint2*)(h1 + px * 68 + Mt * 16 + q * 4) = v;  // 8B-aligned
            }
        cfence();
        if (more) { STAGE(xg_nt, 0, b1); cfence(); }  // spread issue point #2

        f32x4 acc2[2][2];
#pragma unroll
        for (int Mt = 0; Mt < 2; ++Mt)
#pragma unroll
            for (int Nt = 0; Nt < 2; ++Nt) acc2[Mt][Nt] = (f32x4){0.f, 0.f, 0.f, 0.f};
#pragma unroll
        for (int Nt = 0; Nt < 2; ++Nt)
#pragma unroll
            for (int kc = 0; kc < 2; ++kc) {
                int off = (Nt * 16 + n) * 68 + kc * 32 + q * 8;
                uint2 lo = *(const uint2*)(h1 + off);
                uint2 hi = *(const uint2*)(h1 + off + 4);
                union { bf16x8 v; unsigned u[4]; } bb;
                bb.u[0] = lo.x; bb.u[1] = lo.y; bb.u[2] = hi.x; bb.u[3] = hi.y;
#pragma unroll
                for (int Mt = 0; Mt < 2; ++Mt)
                    acc2[Mt][Nt] = __builtin_amdgcn_mfma_f32_16x16x32_bf16(a2[Mt][kc], bb.v, acc2[Mt][Nt], 0, 0, 0);
            }
        cfence();
        if (more) { STAGE(xg_nt, 1, b2); cfence(); }  // spread issue point #3

        short* h2 = (short*)Sw;  // [32 px][32 ch] stride 36 shorts
#pragma unroll
        for (int Mt = 0; Mt < 2; ++Mt)
#pragma unroll
            for (int Nt = 0; Nt < 2; ++Nt) {
                int px = Nt * 16 + n;
                uint2 v;
                v.x = pk2(leaky(acc2[Mt][Nt][0]), leaky(acc2[Mt][Nt][1]));
                v.y = pk2(leaky(acc2[Mt][Nt][2]), leaky(acc2[Mt][Nt][3]));
                *(uint2*)(h2 + px * 36 + Mt * 16 + q * 4) = v;
            }
        cfence();

        f32x4 acc3[2];
#pragma unroll
        for (int Nt = 0; Nt < 2; ++Nt) {
            int off = (Nt * 16 + n) * 36 + q * 8;
            uint2 lo = *(const uint2*)(h2 + off);
            uint2 hi = *(const uint2*)(h2 + off + 4);
            union { bf16x8 v; unsigned u[4]; } bb;
            bb.u[0] = lo.x; bb.u[1] = lo.y; bb.u[2] = hi.x; bb.u[3] = hi.y;
            f32x4 zero = {0.f, 0.f, 0.f, 0.f};
            acc3[Nt] = __builtin_amdgcn_mfma_f32_16x16x32_bf16(a3, bb.v, zero, 0, 0, 0);
        }
        cfence();

        float* h3 = Sw;  // [32 px][16 ch] stride 18 floats
#pragma unroll
        for (int Nt = 0; Nt < 2; ++Nt) {
            int px = Nt * 16 + n;
            f32x2 va = {leaky(acc3[Nt][0]), leaky(acc3[Nt][1])};
            f32x2 vb = {leaky(acc3[Nt][2]), leaky(acc3[Nt][3])};
            *(f32x2*)(h3 + px * 18 + q * 4)     = va;
            *(f32x2*)(h3 + px * 18 + q * 4 + 2) = vb;
        }
        cfence();
        if (more) { STAGE(xg_nt, 2, bt); cfence(); }  // spread issue point #4

        // ---- tail L4-L7, split across half-waves (K-sum halves + shfl_xor 32) ----
        float hh[8];
#pragma unroll
        for (int c = 0; c < 8; ++c) hh[c] = h3[pl * 18 + half * 8 + c];

        float g4[8];
#pragma unroll
        for (int o = 0; o < 8; ++o) {
            float a = 0.f;
#pragma unroll
            for (int c = 0; c < 8; ++c) a = fmaf(lds_tw[o * 16 + half * 8 + c], hh[c], a);
            a += __shfl_xor(a, 32, 64);
            g4[o] = leaky(a);
        }
        float g5[4];
#pragma unroll
        for (int o = 0; o < 4; ++o) {
            float a = 0.f;
#pragma unroll
            for (int c = 0; c < 4; ++c)
                a = fmaf(lds_tw[128 + o * 8 + half * 4 + c], g4[half * 4 + c], a);
            a += __shfl_xor(a, 32, 64);
            g5[o] = leaky(a);
        }
        float g6[2];
#pragma unroll
        for (int o = 0; o < 2; ++o) {
            float a = fmaf(lds_tw[160 + o * 4 + half * 2], g5[half * 2],
                           lds_tw[160 + o * 4 + half * 2 + 1] * g5[half * 2 + 1]);
            a += __shfl_xor(a, 32, 64);
            g6[o] = leaky(a);
        }
        float a7 = lds_tw[168 + half] * g6[half];
        float res = a7 + __shfl_xor(a7, 32, 64);
        if (lane < 32) out[b * 128 + it * 65536 + w * 32 + pl] = res;  // 1 VMEM op (counted)
        cfence();

        bt = b1;  // (t+1)%3
    }
#undef STAGE
}

extern "C" void kernel_launch(void* const* d_in, const int* in_sizes, int n_in,
                              void* d_out, int out_size, void* d_ws, size_t ws_size,
                              hipStream_t stream) {
    const float* x  = (const float*)d_in[0];
    const float* w1 = (const float*)d_in[1];
    const float* w2 = (const float*)d_in[2];
    const float* w3 = (const float*)d_in[3];
    const float* w4 = (const float*)d_in[4];
    const float* w5 = (const float*)d_in[5];
    const float* w6 = (const float*)d_in[6];
    const float* w7 = (const float*)d_in[7];
    float* out = (float*)d_out;

    fused_spread_kernel<<<GRID, 256, 0, stream>>>(x, w1, w2, w3, w4, w5, w6, w7, out);
}

// Round 6
// 375.151 us; speedup vs baseline: 1.0177x; 1.0075x over previous
//
#include <hip/hip_runtime.h>

// Fused 7-layer 1x1-conv chain, round 9: MFMA tail (L4-L7 on the matrix pipe).
//  - Persistent: grid=512 (2 blocks/CU); block owns a 128-px column, loops 8
//    batches. Ring-3 staging + spread issue points + vmcnt gates UNCHANGED from
//    round 8 (audited identical VMEM op order).
//  - KEY CHANGE: scalar L4-L7 tail (85 loop-invariant ds_read_b32 of tail weights
//    + 85 fma + 7-deep shfl_xor chain per wave-tile ~= 500cyc LDS-pipe issue and
//    a long VMEM-silent serial chain) is replaced by the same MFMA bounce pattern
//    as L2/L3, zero-padded: L4 16->8 (K pad 32), L5 8->4, L6 4->2, L7 2->1.
//    A-frags for w4/w5/w6 are one-time per-block loads (12 VGPRs, clamped
//    addresses so masked lanes can't fault); w7 = 2 scalars. Tail LDS ops drop
//    108 -> ~17 per wave-tile; MFMA pipe was ~3% busy - 8 extra MFMAs are free.
//  - lds_tw is GONE, and with it the last __syncthreads: all LDS is wave-private.
//  - px XOR-swizzle via pre-swizzled GLOBAL source (dest lane-linear), L1 B-frag
//    ds_read 4-way -> 2-way. Epilogue scratch separate from ring. 2 blocks/CU.
//
// MFMA 16x16x32 layouts: A[m][k]: m=lane&15, k=(lane>>4)*8+j
//                        B[k][n]: n=lane&15, k=(lane>>4)*8+j
//                        C/D: col=lane&15, row=(lane>>4)*4+reg

#define NEG_SLOPE 0.01f
constexpr int HW = 65536;                     // 256*256
constexpr int GRID = 512;                     // 2 blocks/CU exactly
constexpr int TPB  = 8;                       // tiles per block (= batch count)
constexpr size_t TSTRIDE = (size_t)128 * HW;  // floats between a block's tiles

typedef __attribute__((ext_vector_type(8))) short bf16x8;
typedef __attribute__((ext_vector_type(4))) float f32x4;

__device__ __forceinline__ float leaky(float v) { return fmaxf(v, v * NEG_SLOPE); }

// fp32 pair -> packed bf16x2 (compiler emits v_cvt_pk_bf16_f32; m240: no hand asm)
__device__ __forceinline__ unsigned pk2(float a, float b) {
    __bf16 ba = (__bf16)a, bb = (__bf16)b;
    unsigned short ua = __builtin_bit_cast(unsigned short, ba);
    unsigned short ub = __builtin_bit_cast(unsigned short, bb);
    return (unsigned)ua | ((unsigned)ub << 16);
}

// A-frag from o-major fp32 weight matrix W[m][k] (row length C); k 8-aligned
__device__ __forceinline__ bf16x8 loadA(const float* __restrict__ wsrc, int C, int m, int k) {
    f32x4 lo = *(const f32x4*)(wsrc + m * C + k);
    f32x4 hi = *(const f32x4*)(wsrc + m * C + k + 4);
    union { bf16x8 v; unsigned u[4]; } r;
    r.u[0] = pk2(lo[0], lo[1]); r.u[1] = pk2(lo[2], lo[3]);
    r.u[2] = pk2(hi[0], hi[1]); r.u[3] = pk2(hi[2], hi[3]);
    return r.v;
}

__device__ __forceinline__ void async_cp16(const float* g, float* l) {
    __builtin_amdgcn_global_load_lds((const __attribute__((address_space(1))) unsigned*)g,
                                     (__attribute__((address_space(3))) unsigned*)l,
                                     16, 0, 0);
}

// 0-instruction compiler memory fence (stops TBAA cross-type reordering)
__device__ __forceinline__ void cfence() { asm volatile("" ::: "memory"); }

__global__ __launch_bounds__(256, 2) void fused_mfmatail_kernel(
    const float* __restrict__ x,
    const float* __restrict__ w1, const float* __restrict__ w2,
    const float* __restrict__ w3, const float* __restrict__ w4,
    const float* __restrict__ w5, const float* __restrict__ w6,
    const float* __restrict__ w7, float* __restrict__ out) {
    __shared__ float lds_x[4][3][1024];  // per-wave ring-3: [32 ch][32 px] fp32 (px swizzled)
    __shared__ float lds_s[4][1088];     // per-wave epilogue scratch h1..h6 (4352 B)

    const int tid = threadIdx.x;
    const int w    = tid >> 6;
    const int lane = tid & 63;
    const int n    = lane & 15;       // frag minor index
    const int q    = lane >> 4;       // quad
    const int pl   = lane & 31;
    const int r    = lane >> 3;       // stage: channel row within instr
    const int s4   = (lane & 7) * 4;  // stage: 4-px slot

    const int b = blockIdx.x;
    // tile it: px0 = b*128 + it*65536 -> batch=it, pin=b*128
    const float* xg = x + b * 128 + w * 32;  // + it*TSTRIDE + ch*HW

    // ---- weights once per block (amortized over 8 tiles; L2-hot) ----
    bf16x8 a1[4][4];  // L1: M=64 (4 Mt) x K=128 (4 kc)
#pragma unroll
    for (int Mt = 0; Mt < 4; ++Mt)
#pragma unroll
        for (int kc = 0; kc < 4; ++kc)
            a1[Mt][kc] = loadA(w1, 128, Mt * 16 + n, kc * 32 + q * 8);
    bf16x8 a2[2][2];  // L2: M=32 x K=64
#pragma unroll
    for (int Mt = 0; Mt < 2; ++Mt)
#pragma unroll
        for (int kc = 0; kc < 2; ++kc)
            a2[Mt][kc] = loadA(w2, 64, Mt * 16 + n, kc * 32 + q * 8);
    bf16x8 a3 = loadA(w3, 32, n, q * 8);  // L3: M=16 x K=32

    // tail A-frags, zero-padded (clamped addresses -> no OOB even if speculated)
    const bf16x8 zero8 = {0, 0, 0, 0, 0, 0, 0, 0};
    bf16x8 t4 = loadA(w4, 16, n & 7, (q & 1) * 8);   // w4: [8][16]
    bf16x8 a4 = (n < 8 && q < 2) ? t4 : zero8;       // m=n<8, k=q*8+j<16
    bf16x8 t5 = loadA(w5, 8, n & 3, 0);              // w5: [4][8]
    bf16x8 a5 = (n < 4 && q == 0) ? t5 : zero8;      // m=n<4, k=j<8
    bf16x8 a6 = zero8;                               // w6: [2][4] -> m=n<2, k=j<4
    {
        f32x4 lo = *(const f32x4*)(w6 + (n & 1) * 4);
        union { bf16x8 v; unsigned u[4]; } r6;
        r6.u[0] = pk2(lo[0], lo[1]); r6.u[1] = pk2(lo[2], lo[3]);
        r6.u[2] = 0; r6.u[3] = 0;
        if (n < 2 && q == 0) a6 = r6.v;
    }
    const float w7a = w7[0], w7b = w7[1];            // uniform -> s_load
    cfence();
    __builtin_amdgcn_sched_barrier(0);

    // stage chunk (channels KCX*32..+31, 32 px) of tile at BASE into ring buf BUF.
    // instr i_: channels KCX*32 + i_*8 + r; LDS dest lane-linear (base + lane*16B);
    // global px slot pre-swizzled s4 ^ (i_*8) so LDS[ch][u] = x[ch][u ^ 8*chgrp].
    float* ldsw = &lds_x[w][0][0];
#define STAGE(BASE, KCX, BUF) do {                                                   \
        const float* gb_ = (BASE) + (size_t)((KCX) * 32 + r) * HW;                   \
        float* lb_ = ldsw + (BUF) * 1024;                                            \
        _Pragma("unroll")                                                            \
        for (int i_ = 0; i_ < 4; ++i_)                                               \
            async_cp16(gb_ + (size_t)(i_ * 8) * HW + (s4 ^ (i_ * 8)), lb_ + i_ * 256); \
    } while (0)

    // prologue: chunks 0,1,2 of tile 0 -> bufs 0,1,2  (buf(g) = (t+kc)%3, t=0)
    STAGE(xg, 0, 0);
    STAGE(xg, 1, 1);
    STAGE(xg, 2, 2);
    cfence();

    const int pq = q * 8;
    int bt = 0;  // buf of chunk (t,0) = t%3

    for (int it = 0; it < TPB; ++it) {
        const float* xg_it = xg + (size_t)it * TSTRIDE;
        const float* xg_nt = xg_it + TSTRIDE;
        const bool   more  = (it < TPB - 1);

        int b1 = bt + 1; if (b1 >= 3) b1 -= 3;
        int b2 = bt + 2; if (b2 >= 3) b2 -= 3;
        const int bufk[4] = {bt, b1, b2, bt};  // compute buffers for kc=0..3

        f32x4 acc1[4][2];
#pragma unroll
        for (int Mt = 0; Mt < 4; ++Mt)
#pragma unroll
            for (int Nt = 0; Nt < 2; ++Nt) acc1[Mt][Nt] = (f32x4){0.f, 0.f, 0.f, 0.f};

#pragma unroll
        for (int kc = 0; kc < 4; ++kc) {
            // gate chunk (it,kc); audited younger-op counts (unchanged from r8)
            if (kc <= 1) {
                if (it == 0) asm volatile("s_waitcnt vmcnt(8)" ::: "memory");
                else         asm volatile("s_waitcnt vmcnt(9)" ::: "memory");
            } else if (kc == 2) {
                if (it == 0) asm volatile("s_waitcnt vmcnt(4)" ::: "memory");
                else         asm volatile("s_waitcnt vmcnt(5)" ::: "memory");
            } else {
                asm volatile("s_waitcnt vmcnt(0)" ::: "memory");  // == wait chunk (t,3)
            }
            __builtin_amdgcn_sched_barrier(0);

            const float* xb = ldsw + bufk[kc] * 1024;
#pragma unroll
            for (int Nt = 0; Nt < 2; ++Nt) {
                const int pxsw = (Nt * 16 + n) ^ pq;  // swizzled px slot (2-way banks = free)
                float t[8];
#pragma unroll
                for (int j = 0; j < 8; ++j)
                    t[j] = xb[(pq + j) * 32 + pxsw];
                union { bf16x8 v; unsigned u[4]; } bb;
                bb.u[0] = pk2(t[0], t[1]); bb.u[1] = pk2(t[2], t[3]);
                bb.u[2] = pk2(t[4], t[5]); bb.u[3] = pk2(t[6], t[7]);
#pragma unroll
                for (int Mt = 0; Mt < 4; ++Mt)
                    acc1[Mt][Nt] = __builtin_amdgcn_mfma_f32_16x16x32_bf16(a1[Mt][kc], bb.v, acc1[Mt][Nt], 0, 0, 0);
            }
            __builtin_amdgcn_sched_barrier(0);

            // only chunk (t,3) is staged inside the L1 phase (WAR on buf bt).
            if (kc == 0) { STAGE(xg_it, 3, bt); cfence(); }
        }

        // ---- epilogue (wave-private scratch; per-wave DS in-order => no barriers) ----
        float* Sw = &lds_s[w][0];
        short* h1 = (short*)Sw;  // [32 px][64 ch] stride 68 shorts
#pragma unroll
        for (int Mt = 0; Mt < 4; ++Mt)
#pragma unroll
            for (int Nt = 0; Nt < 2; ++Nt) {
                int px = Nt * 16 + n;
                uint2 v;
                v.x = pk2(leaky(acc1[Mt][Nt][0]), leaky(acc1[Mt][Nt][1]));
                v.y = pk2(leaky(acc1[Mt][Nt][2]), leaky(acc1[Mt][Nt][3]));
                *(uint2*)(h1 + px * 68 + Mt * 16 + q * 4) = v;  // 8B-aligned
            }
        cfence();
        if (more) { STAGE(xg_nt, 0, b1); cfence(); }  // spread issue point #2

        f32x4 acc2[2][2];
#pragma unroll
        for (int Mt = 0; Mt < 2; ++Mt)
#pragma unroll
            for (int Nt = 0; Nt < 2; ++Nt) acc2[Mt][Nt] = (f32x4){0.f, 0.f, 0.f, 0.f};
#pragma unroll
        for (int Nt = 0; Nt < 2; ++Nt)
#pragma unroll
            for (int kc = 0; kc < 2; ++kc) {
                int off = (Nt * 16 + n) * 68 + kc * 32 + q * 8;
                uint2 lo = *(const uint2*)(h1 + off);
                uint2 hi = *(const uint2*)(h1 + off + 4);
                union { bf16x8 v; unsigned u[4]; } bb;
                bb.u[0] = lo.x; bb.u[1] = lo.y; bb.u[2] = hi.x; bb.u[3] = hi.y;
#pragma unroll
                for (int Mt = 0; Mt < 2; ++Mt)
                    acc2[Mt][Nt] = __builtin_amdgcn_mfma_f32_16x16x32_bf16(a2[Mt][kc], bb.v, acc2[Mt][Nt], 0, 0, 0);
            }
        cfence();
        if (more) { STAGE(xg_nt, 1, b2); cfence(); }  // spread issue point #3

        short* h2 = (short*)Sw;  // [32 px][32 ch] stride 36 shorts
#pragma unroll
        for (int Mt = 0; Mt < 2; ++Mt)
#pragma unroll
            for (int Nt = 0; Nt < 2; ++Nt) {
                int px = Nt * 16 + n;
                uint2 v;
                v.x = pk2(leaky(acc2[Mt][Nt][0]), leaky(acc2[Mt][Nt][1]));
                v.y = pk2(leaky(acc2[Mt][Nt][2]), leaky(acc2[Mt][Nt][3]));
                *(uint2*)(h2 + px * 36 + Mt * 16 + q * 4) = v;
            }
        cfence();

        f32x4 acc3[2];
#pragma unroll
        for (int Nt = 0; Nt < 2; ++Nt) {
            int off = (Nt * 16 + n) * 36 + q * 8;
            uint2 lo = *(const uint2*)(h2 + off);
            uint2 hi = *(const uint2*)(h2 + off + 4);
            union { bf16x8 v; unsigned u[4]; } bb;
            bb.u[0] = lo.x; bb.u[1] = lo.y; bb.u[2] = hi.x; bb.u[3] = hi.y;
            f32x4 zero = {0.f, 0.f, 0.f, 0.f};
            acc3[Nt] = __builtin_amdgcn_mfma_f32_16x16x32_bf16(a3, bb.v, zero, 0, 0, 0);
        }
        cfence();

        // ---- MFMA tail: h3 [32px][16ch] bf16 stride 24 shorts (16B-aligned rows) ----
        short* h3 = (short*)Sw;
#pragma unroll
        for (int Nt = 0; Nt < 2; ++Nt) {
            int px = Nt * 16 + n;  // C rows = ch q*4+reg (all 16 ch)
            uint2 v;
            v.x = pk2(leaky(acc3[Nt][0]), leaky(acc3[Nt][1]));
            v.y = pk2(leaky(acc3[Nt][2]), leaky(acc3[Nt][3]));
            *(uint2*)(h3 + px * 24 + q * 4) = v;  // byte 48px+8q, 8B-aligned
        }
        cfence();
        if (more) { STAGE(xg_nt, 2, bt); cfence(); }  // spread issue point #4

        // L4: 16 -> 8 (K=16 pad 32). B k=q*8+j: real for q<2.
        f32x4 acc4[2];
#pragma unroll
        for (int Nt = 0; Nt < 2; ++Nt) {
            int px = Nt * 16 + n;
            uint4 t = *(const uint4*)(h3 + px * 24 + (q & 1) * 8);  // byte 48px+16(q&1), 16B-aligned
            union { bf16x8 v; unsigned u[4]; } bb;
            bool z = (q >= 2);
            bb.u[0] = z ? 0u : t.x; bb.u[1] = z ? 0u : t.y;
            bb.u[2] = z ? 0u : t.z; bb.u[3] = z ? 0u : t.w;
            f32x4 zero = {0.f, 0.f, 0.f, 0.f};
            acc4[Nt] = __builtin_amdgcn_mfma_f32_16x16x32_bf16(a4, bb.v, zero, 0, 0, 0);
        }
        cfence();

        short* h4 = (short*)Sw;  // [32px][8ch] stride 12 shorts; valid C rows 0-7 (q<2)
#pragma unroll
        for (int Nt = 0; Nt < 2; ++Nt) {
            if (q < 2) {
                int px = Nt * 16 + n;
                uint2 v;
                v.x = pk2(leaky(acc4[Nt][0]), leaky(acc4[Nt][1]));
                v.y = pk2(leaky(acc4[Nt][2]), leaky(acc4[Nt][3]));
                *(uint2*)(h4 + px * 12 + q * 4) = v;  // byte 24px+8q, 8B-aligned
            }
        }
        cfence();

        // L5: 8 -> 4 (K=8 pad 32). B real only for q==0 (same addr per n -> broadcast).
        f32x4 acc5[2];
#pragma unroll
        for (int Nt = 0; Nt < 2; ++Nt) {
            int px = Nt * 16 + n;
            uint2 lo = *(const uint2*)(h4 + px * 12);
            uint2 hi = *(const uint2*)(h4 + px * 12 + 4);
            union { bf16x8 v; unsigned u[4]; } bb;
            bool z = (q != 0);
            bb.u[0] = z ? 0u : lo.x; bb.u[1] = z ? 0u : lo.y;
            bb.u[2] = z ? 0u : hi.x; bb.u[3] = z ? 0u : hi.y;
            f32x4 zero = {0.f, 0.f, 0.f, 0.f};
            acc5[Nt] = __builtin_amdgcn_mfma_f32_16x16x32_bf16(a5, bb.v, zero, 0, 0, 0);
        }
        cfence();

        short* h5 = (short*)Sw;  // [32px][4ch] stride 8 shorts; valid C rows 0-3 (q==0)
#pragma unroll
        for (int Nt = 0; Nt < 2; ++Nt) {
            if (q == 0) {
                int px = Nt * 16 + n;
                uint2 v;
                v.x = pk2(leaky(acc5[Nt][0]), leaky(acc5[Nt][1]));
                v.y = pk2(leaky(acc5[Nt][2]), leaky(acc5[Nt][3]));
                *(uint2*)(h5 + px * 8) = v;  // byte 16px, 8B-aligned
            }
        }
        cfence();

        // L6: 4 -> 2 (K=4 pad 32). B real only for q==0, j<4.
        f32x4 acc6[2];
#pragma unroll
        for (int Nt = 0; Nt < 2; ++Nt) {
            int px = Nt * 16 + n;
            uint2 lo = *(const uint2*)(h5 + px * 8);
            union { bf16x8 v; unsigned u[4]; } bb;
            bool z = (q != 0);
            bb.u[0] = z ? 0u : lo.x; bb.u[1] = z ? 0u : lo.y;
            bb.u[2] = 0u; bb.u[3] = 0u;
            f32x4 zero = {0.f, 0.f, 0.f, 0.f};
            acc6[Nt] = __builtin_amdgcn_mfma_f32_16x16x32_bf16(a6, bb.v, zero, 0, 0, 0);
        }
        cfence();

        short* h6 = (short*)Sw;  // [32px][2ch] dense stride 2 shorts; valid rows 0-1 (q==0)
#pragma unroll
        for (int Nt = 0; Nt < 2; ++Nt) {
            if (q == 0) {
                int px = Nt * 16 + n;
                *(unsigned*)(h6 + px * 2) = pk2(leaky(acc6[Nt][0]), leaky(acc6[Nt][1]));
            }
        }
        cfence();

        // L7: 2 -> 1, no activation. Lane pl reads px=pl (halves duplicate).
        unsigned cc = *(const unsigned*)(h6 + pl * 2);
        float c0 = __uint_as_float(cc << 16);
        float c1 = __uint_as_float(cc & 0xffff0000u);
        float res = fmaf(w7a, c0, w7b * c1);
        if (lane < 32) out[b * 128 + it * 65536 + w * 32 + pl] = res;  // 1 VMEM op (counted)
        cfence();

        bt = b1;  // (t+1)%3
    }
#undef STAGE
}

extern "C" void kernel_launch(void* const* d_in, const int* in_sizes, int n_in,
                              void* d_out, int out_size, void* d_ws, size_t ws_size,
                              hipStream_t stream) {
    const float* x  = (const float*)d_in[0];
    const float* w1 = (const float*)d_in[1];
    const float* w2 = (const float*)d_in[2];
    const float* w3 = (const float*)d_in[3];
    const float* w4 = (const float*)d_in[4];
    const float* w5 = (const float*)d_in[5];
    const float* w6 = (const float*)d_in[6];
    const float* w7 = (const float*)d_in[7];
    float* out = (float*)d_out;

    fused_mfmatail_kernel<<<GRID, 256, 0, stream>>>(x, w1, w2, w3, w4, w5, w6, w7, out);
}